// Round 6
// baseline (2756.996 us; speedup 1.0000x reference)
//
#include <hip/hip_runtime.h>
#include <math.h>

// R6: revert GEMM K-loops to the R0-proven simple m97 structure.
//  R5 post-mortem: dbuf + raw barriers + sched_barrier(0) REGRESSED gemm_bf<1>
//  vs R0 (<=88 -> 99us) — the documented m141 anti-pattern (order-pinning
//  defeats the compiler's scheduling; m131-m140: source-level pipelining never
//  beats the m97 structure). Revert to single-buffer + __syncthreads.
//  KEEP the independently-justified wins: XCD swizzle, chunk-XOR LDS swizzle
//  (bank conflicts 3.7M->0), and non-atomic k_gemm_w2 (R5's +450us win).

// ---- problem constants ----
#define BB 32
#define SS 197
#define DD 768
#define HH 12
#define DHD 64
#define LL 12
#define FF 3072
#define NPATCH 196
#define NTOK (BB * SS)          // 6304
#define MPAD 6400               // NTOK padded to multiple of 128
#define LNEPS 1e-5f

typedef short bf8_t __attribute__((ext_vector_type(8)));
typedef float f4_t  __attribute__((ext_vector_type(4)));
typedef unsigned short u16x8 __attribute__((ext_vector_type(8)));

__device__ __forceinline__ unsigned short f2bf(float x) {
    unsigned u = __float_as_uint(x);
    return (unsigned short)((u + 0x8000u) >> 16);
}
__device__ __forceinline__ float bf_lo(unsigned u) { return __uint_as_float(u << 16); }

__device__ __forceinline__ void gl_lds16(const void* g, void* l) {
    __builtin_amdgcn_global_load_lds((const __attribute__((address_space(1))) unsigned int*)g,
                                     (__attribute__((address_space(3))) unsigned int*)l, 16, 0, 0);
}

// bijective XCD-aware block swizzle (m204 variant; works for any nwg)
__device__ __forceinline__ int xcd_swz(int bid, int nwg) {
    const int q = nwg >> 3, r = nwg & 7;
    const int xcd = bid & 7, idx = bid >> 3;
    return (xcd < r ? xcd * (q + 1) : r * (q + 1) + (xcd - r) * q) + idx;
}

// =====================================================================
// fp32 -> bf16 converters
// =====================================================================
__global__ __launch_bounds__(256) void k_conv(const float* __restrict__ a,
                                              unsigned short* __restrict__ o, int n4) {
    for (int i = blockIdx.x * 256 + threadIdx.x; i < n4; i += gridDim.x * 256) {
        float4 v = ((const float4*)a)[i];
        ushort4 r;
        r.x = f2bf(v.x); r.y = f2bf(v.y); r.z = f2bf(v.z); r.w = f2bf(v.w);
        ((ushort4*)o)[i] = r;
    }
}

// two tensors in one launch (per-layer W1+W2)
__global__ __launch_bounds__(256) void k_conv2(const float* __restrict__ a1,
                                               unsigned short* __restrict__ o1, int n1,
                                               const float* __restrict__ a2,
                                               unsigned short* __restrict__ o2, int n2) {
    for (int i = blockIdx.x * 256 + threadIdx.x; i < n1 + n2; i += gridDim.x * 256) {
        const float* a = (i < n1) ? a1 : a2;
        unsigned short* o = (i < n1) ? o1 : o2;
        int j = (i < n1) ? i : i - n1;
        float4 v = ((const float4*)a)[j];
        ushort4 r;
        r.x = f2bf(v.x); r.y = f2bf(v.y); r.z = f2bf(v.z); r.w = f2bf(v.w);
        ((ushort4*)o)[j] = r;
    }
}

// =====================================================================
// patchify: image [B,3,224,224] -> P_bf [B*196, 768] bf16, order (c,pi,pj)
// =====================================================================
__global__ __launch_bounds__(256) void k_patchify(const float* __restrict__ img,
                                                  unsigned short* __restrict__ P) {
    const int total = BB * NPATCH * DD;
    for (int idx = blockIdx.x * 256 + threadIdx.x; idx < total; idx += gridDim.x * 256) {
        int e = idx % DD;
        int rest = idx / DD;
        int p = rest % NPATCH;
        int b = rest / NPATCH;
        int c = e >> 8;
        int pi = (e >> 4) & 15;
        int pj = e & 15;
        int i = p / 14, j = p % 14;
        P[idx] = f2bf(img[(((size_t)b * 3 + c) * 224 + (i * 16 + pi)) * 224 + (j * 16 + pj)]);
    }
}

// =====================================================================
// bf16 MFMA GEMM (m97 simple structure): C[m,n] = A[m,k] * W[n,k]^T + bias
// EPI: 0 = embed (remap rows, f32 store), 1 = GELU -> bf16, 2 = res add f32
// =====================================================================
template <int EPI>
__global__ __launch_bounds__(256) void k_gemm_bf(const unsigned short* __restrict__ A,
                                                 const unsigned short* __restrict__ Bw,
                                                 const float* __restrict__ bias,
                                                 void* __restrict__ Cout,
                                                 int M, int N, int K) {
    __shared__ unsigned short As[128 * 32];
    __shared__ unsigned short Bs[128 * 32];
    const int tid = threadIdx.x;
    const int wave = tid >> 6, lane = tid & 63;

    const int nwg = gridDim.x * gridDim.y;
    const int sb = xcd_swz(blockIdx.y * gridDim.x + blockIdx.x, nwg);
    const int bx = sb % gridDim.x, by = sb / gridDim.x;
    const int m0 = by << 7, n0 = bx << 7;

    const int r0 = tid >> 2;
    const int kp = (((tid & 3) ^ ((r0 >> 1) & 3)) << 3);   // pre-swizzled source chunk
    const unsigned short* gA0 = A + (size_t)(m0 + r0) * K + kp;
    const unsigned short* gA1 = A + (size_t)(m0 + 64 + r0) * K + kp;
    const unsigned short* gB0 = Bw + (size_t)(n0 + r0) * K + kp;
    const unsigned short* gB1 = Bw + (size_t)(n0 + 64 + r0) * K + kp;
    unsigned short* lA0 = &As[tid * 8];
    unsigned short* lA1 = &As[(tid + 256) * 8];
    unsigned short* lB0 = &Bs[tid * 8];
    unsigned short* lB1 = &Bs[(tid + 256) * 8];

    const int mh = (wave >> 1) << 6, nh = (wave & 1) << 6;
    const int lm = lane & 15, kq = lane >> 4;
    const int kqx = ((kq ^ ((lm >> 1) & 3)) << 3);         // swizzled read chunk (shorts)

    f4_t acc[4][4];
#pragma unroll
    for (int i = 0; i < 4; ++i)
#pragma unroll
        for (int j = 0; j < 4; ++j) acc[i][j] = (f4_t){0.f, 0.f, 0.f, 0.f};

    for (int k0 = 0; k0 < K; k0 += 32) {
        gl_lds16(gA0, lA0);
        gl_lds16(gA1, lA1);
        gl_lds16(gB0, lB0);
        gl_lds16(gB1, lB1);
        gA0 += 32; gA1 += 32; gB0 += 32; gB1 += 32;
        __syncthreads();
        bf8_t af[4], bfr[4];
#pragma unroll
        for (int mt = 0; mt < 4; ++mt)
            af[mt] = *(const bf8_t*)&As[(mh + mt * 16 + lm) * 32 + kqx];
#pragma unroll
        for (int nv = 0; nv < 4; ++nv)
            bfr[nv] = *(const bf8_t*)&Bs[(nh + nv * 16 + lm) * 32 + kqx];
#pragma unroll
        for (int mt = 0; mt < 4; ++mt)
#pragma unroll
            for (int nv = 0; nv < 4; ++nv)
                acc[mt][nv] = __builtin_amdgcn_mfma_f32_16x16x32_bf16(af[mt], bfr[nv],
                                                                      acc[mt][nv], 0, 0, 0);
        __syncthreads();
    }

    const int rbase = m0 + mh + kq * 4;
    const int cbase = n0 + nh + lm;
#pragma unroll
    for (int mt = 0; mt < 4; ++mt) {
#pragma unroll
        for (int nv = 0; nv < 4; ++nv) {
            const int col = cbase + nv * 16;
            const float bv = bias[col];
#pragma unroll
            for (int r = 0; r < 4; ++r) {
                const int row = rbase + mt * 16 + r;
                float val = acc[mt][nv][r] + bv;
                if (EPI == 0) {
                    size_t om = (size_t)(row / 196) * 197 + (row % 196) + 1;
                    ((float*)Cout)[om * DD + col] = val;
                } else if (EPI == 1) {
                    val = 0.5f * val * (1.f + erff(val * 0.7071067811865476f));
                    ((unsigned short*)Cout)[(size_t)row * N + col] = f2bf(val);
                } else {
                    if (row < M) ((float*)Cout)[(size_t)row * DD + col] += val;
                }
            }
        }
    }
}

// =====================================================================
// W2 GEMM, no split-K, 128x64 tile, m97 simple structure:
// x[m, n] += A[m,k] * W2[n,k]^T + bias.  grid (12, 50) = 600 blocks;
// one owner per output element -> plain RMW epilogue (no atomics).
// Wave layout: 2M x 2N, each wave 64x32 -> acc[4][2].
// =====================================================================
__global__ __launch_bounds__(256) void k_gemm_w2(const unsigned short* __restrict__ A,
                                                 const unsigned short* __restrict__ Bw,
                                                 const float* __restrict__ bias,
                                                 float* __restrict__ x,
                                                 int M, int K) {
    __shared__ unsigned short As[128 * 32];
    __shared__ unsigned short Bs[64 * 32];
    const int tid = threadIdx.x;
    const int wave = tid >> 6, lane = tid & 63;

    const int nwg = gridDim.x * gridDim.y;   // 600
    const int sb = xcd_swz(blockIdx.y * gridDim.x + blockIdx.x, nwg);
    const int bx = sb % gridDim.x, by = sb / gridDim.x;
    const int m0 = by << 7, n0 = bx << 6;

    const int r0 = tid >> 2;
    const int kp = (((tid & 3) ^ ((r0 >> 1) & 3)) << 3);   // pre-swizzled source chunk
    const unsigned short* gA0 = A + (size_t)(m0 + r0) * K + kp;
    const unsigned short* gA1 = A + (size_t)(m0 + 64 + r0) * K + kp;
    const unsigned short* gB0 = Bw + (size_t)(n0 + r0) * K + kp;
    unsigned short* lA0 = &As[tid * 8];
    unsigned short* lA1 = &As[(tid + 256) * 8];
    unsigned short* lB0 = &Bs[tid * 8];

    const int mh = (wave >> 1) << 6, nh = (wave & 1) << 5;
    const int lm = lane & 15, kq = lane >> 4;
    const int kqx = ((kq ^ ((lm >> 1) & 3)) << 3);

    f4_t acc[4][2];
#pragma unroll
    for (int i = 0; i < 4; ++i)
#pragma unroll
        for (int j = 0; j < 2; ++j) acc[i][j] = (f4_t){0.f, 0.f, 0.f, 0.f};

    for (int k0 = 0; k0 < K; k0 += 32) {
        gl_lds16(gA0, lA0);
        gl_lds16(gA1, lA1);
        gl_lds16(gB0, lB0);
        gA0 += 32; gA1 += 32; gB0 += 32;
        __syncthreads();
        bf8_t af[4], bfr[2];
#pragma unroll
        for (int mt = 0; mt < 4; ++mt)
            af[mt] = *(const bf8_t*)&As[(mh + mt * 16 + lm) * 32 + kqx];
#pragma unroll
        for (int nv = 0; nv < 2; ++nv)
            bfr[nv] = *(const bf8_t*)&Bs[(nh + nv * 16 + lm) * 32 + kqx];
#pragma unroll
        for (int mt = 0; mt < 4; ++mt)
#pragma unroll
            for (int nv = 0; nv < 2; ++nv)
                acc[mt][nv] = __builtin_amdgcn_mfma_f32_16x16x32_bf16(af[mt], bfr[nv],
                                                                      acc[mt][nv], 0, 0, 0);
        __syncthreads();
    }

    const int rbase = m0 + mh + kq * 4;
    const int cbase = n0 + nh + lm;
#pragma unroll
    for (int mt = 0; mt < 4; ++mt) {
#pragma unroll
        for (int nv = 0; nv < 2; ++nv) {
            const int col = cbase + nv * 16;
            const float bv = bias[col];
#pragma unroll
            for (int r = 0; r < 4; ++r) {
                const int row = rbase + mt * 16 + r;
                if (row < M)
                    x[(size_t)row * DD + col] += acc[mt][nv][r] + bv;
            }
        }
    }
}

// =====================================================================
// QKV via MFMA: block = (head, 128-token tile). Single-barrier K=64.
// =====================================================================
__global__ __launch_bounds__(256) void k_qkv_mfma(const unsigned short* __restrict__ h,
                                                  const unsigned short* __restrict__ Wqb,
                                                  const unsigned short* __restrict__ Wkb,
                                                  const unsigned short* __restrict__ Wvb,
                                                  const float* __restrict__ bq,
                                                  const float* __restrict__ bk,
                                                  const float* __restrict__ bv,
                                                  unsigned short* __restrict__ qo,
                                                  unsigned short* __restrict__ ko,
                                                  unsigned short* __restrict__ vo) {
    __shared__ unsigned short As[2 * 128 * 32];       // [khalf][row][32]
    __shared__ unsigned short Bs[3 * 2 * 64 * 32];    // [mat][khalf][row][32]
    const int head = blockIdx.x;
    const int m0 = blockIdx.y << 7;
    const int tid = threadIdx.x;
    const int wave = tid >> 6, lane = tid & 63;
    const int lm = lane & 15, kq = lane >> 4;

#pragma unroll
    for (int j = 0; j < 4; ++j) {
        int khalf = j >> 1;
        int rem = (j & 1) * 256 + tid;           // 0..511
        int row = rem >> 2, koff = (rem & 3) * 8;
        gl_lds16(h + (size_t)(m0 + row) * DD + head * 64 + khalf * 32 + koff,
                 &As[(j * 256 + tid) * 8]);
    }
    const unsigned short* Wq_h = Wqb + head * 4096;
    const unsigned short* Wk_h = Wkb + head * 4096;
    const unsigned short* Wv_h = Wvb + head * 4096;
#pragma unroll
    for (int j = 0; j < 6; ++j) {
        const unsigned short* src = (j < 2) ? Wq_h : ((j < 4) ? Wk_h : Wv_h);
        int cm = (j & 1) * 256 + tid;            // 0..511 within mat
        int khalf = cm >> 8;
        int rem2 = cm & 255;
        int row = rem2 >> 2, koff = (rem2 & 3) * 8;
        gl_lds16(src + row * 64 + khalf * 32 + koff, &Bs[(j * 256 + tid) * 8]);
    }
    __syncthreads();

    f4_t acc[2][12];
#pragma unroll
    for (int i = 0; i < 2; ++i)
#pragma unroll
        for (int j = 0; j < 12; ++j) acc[i][j] = (f4_t){0.f, 0.f, 0.f, 0.f};

#pragma unroll
    for (int kh = 0; kh < 2; ++kh) {
        bf8_t af[2], bfr[12];
#pragma unroll
        for (int mt = 0; mt < 2; ++mt)
            af[mt] = *(const bf8_t*)&As[kh * 4096 + (wave * 32 + mt * 16 + lm) * 32 + kq * 8];
#pragma unroll
        for (int nt = 0; nt < 12; ++nt)
            bfr[nt] = *(const bf8_t*)&Bs[(nt >> 2) * 4096 + kh * 2048 +
                                         ((nt & 3) * 16 + lm) * 32 + kq * 8];
#pragma unroll
        for (int mt = 0; mt < 2; ++mt)
#pragma unroll
            for (int nt = 0; nt < 12; ++nt)
                acc[mt][nt] = __builtin_amdgcn_mfma_f32_16x16x32_bf16(af[mt], bfr[nt],
                                                                      acc[mt][nt], 0, 0, 0);
    }

    const int rbase = m0 + wave * 32 + kq * 4;
#pragma unroll
    for (int mt = 0; mt < 2; ++mt) {
#pragma unroll
        for (int nt = 0; nt < 12; ++nt) {
            const int col = nt * 16 + lm;
            const int e = col & 63;
            const float* bsrc = (nt < 4) ? bq : ((nt < 8) ? bk : bv);
            unsigned short* dst = (nt < 4) ? qo : ((nt < 8) ? ko : vo);
            const float bval = bsrc[head * 64 + e];
#pragma unroll
            for (int r = 0; r < 4; ++r) {
                const int row = rbase + mt * 16 + r;
                if (row < NTOK)
                    dst[(size_t)row * DD + head * 64 + e] = f2bf(acc[mt][nt][r] + bval);
            }
        }
    }
}

// =====================================================================
// pos-embed add (+cls for s==0)
// =====================================================================
__global__ __launch_bounds__(256) void k_posadd(float* __restrict__ x,
                                                const float* __restrict__ cls) {
    const int total = BB * SS * DD;
    const float LN1E4 = 9.210340371976184f;
    for (int idx = blockIdx.x * 256 + threadIdx.x; idx < total; idx += gridDim.x * 256) {
        int d = idx % DD;
        int s = (idx / DD) % SS;
        float ang = (float)s * __expf(-LN1E4 * (float)(2 * (d >> 1)) / 768.f);
        float pv = (d & 1) ? __cosf(ang) : __sinf(ang);
        if (s == 0) x[idx] = cls[d] + pv;
        else        x[idx] += pv;
    }
}

// =====================================================================
// LayerNorm: wave per row (4 rows/block), lane holds 12 elems, bf16 out
// =====================================================================
__global__ __launch_bounds__(256) void k_ln2(const float* __restrict__ x,
                                             const float* __restrict__ g,
                                             const float* __restrict__ bp,
                                             unsigned short* __restrict__ out) {
    const int row = blockIdx.x * 4 + (threadIdx.x >> 6);
    const int lane = threadIdx.x & 63;
    if (row >= NTOK) return;
    const float* xr = x + (size_t)row * DD + lane * 12;
    float4 a = ((const float4*)xr)[0];
    float4 b = ((const float4*)xr)[1];
    float4 c = ((const float4*)xr)[2];
    float s = a.x + a.y + a.z + a.w + b.x + b.y + b.z + b.w + c.x + c.y + c.z + c.w;
#pragma unroll
    for (int o = 32; o; o >>= 1) s += __shfl_xor(s, o);
    const float mean = s * (1.f / DD);
    float vr = 0.f, e0;
    e0 = a.x - mean; vr += e0 * e0; e0 = a.y - mean; vr += e0 * e0;
    e0 = a.z - mean; vr += e0 * e0; e0 = a.w - mean; vr += e0 * e0;
    e0 = b.x - mean; vr += e0 * e0; e0 = b.y - mean; vr += e0 * e0;
    e0 = b.z - mean; vr += e0 * e0; e0 = b.w - mean; vr += e0 * e0;
    e0 = c.x - mean; vr += e0 * e0; e0 = c.y - mean; vr += e0 * e0;
    e0 = c.z - mean; vr += e0 * e0; e0 = c.w - mean; vr += e0 * e0;
#pragma unroll
    for (int o = 32; o; o >>= 1) vr += __shfl_xor(vr, o);
    const float rstd = rsqrtf(vr * (1.f / DD) + LNEPS);

    const float4* g4 = (const float4*)(g + lane * 12);
    const float4* b4p = (const float4*)(bp + lane * 12);
    unsigned short* op = out + (size_t)row * DD + lane * 12;
    float4 gv, bv;
    ushort4 r;
    gv = g4[0]; bv = b4p[0];
    r.x = f2bf((a.x - mean) * rstd * gv.x + bv.x);
    r.y = f2bf((a.y - mean) * rstd * gv.y + bv.y);
    r.z = f2bf((a.z - mean) * rstd * gv.z + bv.z);
    r.w = f2bf((a.w - mean) * rstd * gv.w + bv.w);
    ((ushort4*)op)[0] = r;
    gv = g4[1]; bv = b4p[1];
    r.x = f2bf((b.x - mean) * rstd * gv.x + bv.x);
    r.y = f2bf((b.y - mean) * rstd * gv.y + bv.y);
    r.z = f2bf((b.z - mean) * rstd * gv.z + bv.z);
    r.w = f2bf((b.w - mean) * rstd * gv.w + bv.w);
    ((ushort4*)op)[1] = r;
    gv = g4[2]; bv = b4p[2];
    r.x = f2bf((c.x - mean) * rstd * gv.x + bv.x);
    r.y = f2bf((c.y - mean) * rstd * gv.y + bv.y);
    r.z = f2bf((c.z - mean) * rstd * gv.z + bv.z);
    r.w = f2bf((c.w - mean) * rstd * gv.w + bv.w);
    ((ushort4*)op)[2] = r;
}

// =====================================================================
// attention v3 (MFMA): block = (64-query tile, head, b), 256 thr = 4 waves.
// =====================================================================
__global__ __launch_bounds__(256) void k_attn3(const unsigned short* __restrict__ qg,
                                               const unsigned short* __restrict__ kg,
                                               const unsigned short* __restrict__ vg,
                                               float* __restrict__ x) {
    const int qt = blockIdx.x, head = blockIdx.y, b = blockIdx.z;
    const int tid = threadIdx.x, wv = tid >> 6, lane = tid & 63;
    const int lm = lane & 15, kq = lane >> 4;

    __shared__ __align__(16) unsigned short lds[29696];   // 59392 B
    unsigned short* Kl = lds;            // [kh][224][32] = 14336 sh
    unsigned short* Pl = lds;            // [4][16][232]  = 14848 sh (aliases K)
    unsigned short* Vt = lds + 14848;    // [64][232]     = 14848 sh

    const size_t tokbase = (size_t)b * SS;
    const unsigned short* kb = kg + tokbase * DD + head * 64;
    const unsigned short* vb = vg + tokbase * DD + head * 64;
    const unsigned short* qb = qg + tokbase * DD + head * 64;

    // ---- stage K: [kh][t(224)][32], 1792 x 16B chunks via global_load_lds ----
#pragma unroll
    for (int it = 0; it < 7; ++it) {
        int c = it * 256 + tid;
        int kh = c / 896, rem = c - kh * 896;
        int t = rem >> 2, cc = rem & 3;
        gl_lds16(kb + (size_t)t * DD + kh * 32 + cc * 8, (char*)lds + c * 16);
    }
    // ---- stage V transposed: Vt[e][t], t padded 224 (197.. zeroed) ----
#pragma unroll
    for (int it = 0; it < 7; ++it) {
        int idx = it * 256 + tid;
        int t = idx >> 3, eg = idx & 7;
        if (t < SS) {
            u16x8 v8 = *(const u16x8*)(vb + (size_t)t * DD + eg * 8);
#pragma unroll
            for (int j = 0; j < 8; ++j) Vt[(eg * 8 + j) * 232 + t] = v8[j];
        } else {
#pragma unroll
            for (int j = 0; j < 8; ++j) Vt[(eg * 8 + j) * 232 + t] = 0;
        }
    }

    // ---- Q fragments (B-operand) straight from global ----
    const int qrow = qt * 64 + wv * 16 + lm;
    bf8_t qf0 = *(const bf8_t*)(qb + (size_t)qrow * DD + kq * 8);
    bf8_t qf1 = *(const bf8_t*)(qb + (size_t)qrow * DD + 32 + kq * 8);

    __syncthreads();

    // ---- S^T: D[t-tile][q16] ; 13 t-tiles x 2 kh ----
    f4_t sacc[13];
#pragma unroll
    for (int tt = 0; tt < 13; ++tt) sacc[tt] = (f4_t){0.f, 0.f, 0.f, 0.f};
#pragma unroll
    for (int tt = 0; tt < 13; ++tt) {
        bf8_t a0 = *(const bf8_t*)&Kl[(tt * 16 + lm) * 32 + kq * 8];
        bf8_t a1 = *(const bf8_t*)&Kl[7168 + (tt * 16 + lm) * 32 + kq * 8];
        sacc[tt] = __builtin_amdgcn_mfma_f32_16x16x32_bf16(a0, qf0, sacc[tt], 0, 0, 0);
        sacc[tt] = __builtin_amdgcn_mfma_f32_16x16x32_bf16(a1, qf1, sacc[tt], 0, 0, 0);
    }

    // ---- softmax over t for q = lm ----
    float mx = -1e30f;
#pragma unroll
    for (int tt = 0; tt < 13; ++tt)
#pragma unroll
        for (int r = 0; r < 4; ++r) {
            float s = sacc[tt][r] * 0.125f;
            if (tt == 12 && (kq * 4 + r) >= 5) s = -1e30f;   // t >= 197
            sacc[tt][r] = s;
            mx = fmaxf(mx, s);
        }
    mx = fmaxf(mx, __shfl_xor(mx, 16));
    mx = fmaxf(mx, __shfl_xor(mx, 32));
    float sum = 0.f;
#pragma unroll
    for (int tt = 0; tt < 13; ++tt)
#pragma unroll
        for (int r = 0; r < 4; ++r) {
            float p = __expf(sacc[tt][r] - mx);
            sacc[tt][r] = p;
            sum += p;
        }
    sum += __shfl_xor(sum, 16);
    sum += __shfl_xor(sum, 32);
    const float inv = 1.f / sum;

    __syncthreads();   // all waves done reading K -> safe to overwrite with P

    // ---- write P (A-layout rows [q][t], per-wave region) ----
    unsigned short* Pw = Pl + wv * 3712;
#pragma unroll
    for (int tt = 0; tt < 13; ++tt)
#pragma unroll
        for (int r = 0; r < 4; ++r)
            Pw[lm * 232 + tt * 16 + kq * 4 + r] = f2bf(sacc[tt][r]);
    *(short4*)&Pw[lm * 232 + 208 + kq * 4] = make_short4(0, 0, 0, 0);

    // ---- PV: O[q][e] ; 7 k-chunks x 4 e-tiles ----
    f4_t oacc[4];
#pragma unroll
    for (int et = 0; et < 4; ++et) oacc[et] = (f4_t){0.f, 0.f, 0.f, 0.f};
#pragma unroll
    for (int kc = 0; kc < 7; ++kc) {
        bf8_t pa = *(const bf8_t*)&Pw[lm * 232 + kc * 32 + kq * 8];
#pragma unroll
        for (int et = 0; et < 4; ++et) {
            bf8_t vv = *(const bf8_t*)&Vt[(et * 16 + lm) * 232 + kc * 32 + kq * 8];
            oacc[et] = __builtin_amdgcn_mfma_f32_16x16x32_bf16(pa, vv, oacc[et], 0, 0, 0);
        }
    }

    // ---- 1/sum redistribution (softmax layout q=lm -> C layout q=kq*4+r) ----
    float invq[4];
#pragma unroll
    for (int r = 0; r < 4; ++r) invq[r] = __shfl(inv, kq * 4 + r);

    // ---- residual add into x ----
    float* xp = x + tokbase * DD + head * 64;
#pragma unroll
    for (int r = 0; r < 4; ++r) {
        const int qgr = qt * 64 + wv * 16 + kq * 4 + r;
        if (qgr < SS) {
#pragma unroll
            for (int et = 0; et < 4; ++et)
                xp[(size_t)qgr * DD + et * 16 + lm] += oacc[et][r] * invq[r];
        }
    }
}

// =====================================================================
// classifier head (fp32)
// =====================================================================
__global__ __launch_bounds__(256) void k_head(const float* __restrict__ x,
                                              const float* __restrict__ Wh,
                                              const float* __restrict__ bh,
                                              float* __restrict__ out) {
    const int b = blockIdx.y;
    const int c = blockIdx.x * 256 + threadIdx.x;
    __shared__ __align__(16) float xs[DD];
    const float* xr = x + (size_t)b * SS * DD;
    for (int d = threadIdx.x; d < DD; d += 256) xs[d] = xr[d];
    __syncthreads();
    if (c < 1000) {
        const float4* w4 = (const float4*)(Wh + (size_t)c * DD);
        float acc = 0.f;
#pragma unroll 4
        for (int d4 = 0; d4 < DD / 4; ++d4) {
            float4 w = w4[d4];
            const float4 xv = *(const float4*)&xs[d4 << 2];
            acc += xv.x * w.x + xv.y * w.y + xv.z * w.z + xv.w * w.w;
        }
        out[(size_t)b * 1000 + c] = acc + bh[c];
    }
}

// =====================================================================
extern "C" void kernel_launch(void* const* d_in, const int* in_sizes, int n_in,
                              void* d_out, int out_size, void* d_ws, size_t ws_size,
                              hipStream_t stream) {
    const float* image   = (const float*)d_in[0];
    const float* W_embed = (const float*)d_in[1];
    const float* b_embed = (const float*)d_in[2];
    const float* cls     = (const float*)d_in[3];
    const float* Wq      = (const float*)d_in[4];
    const float* bq      = (const float*)d_in[5];
    const float* Wk      = (const float*)d_in[6];
    const float* bk      = (const float*)d_in[7];
    const float* Wv      = (const float*)d_in[8];
    const float* bv      = (const float*)d_in[9];
    const float* ln1g    = (const float*)d_in[10];
    const float* ln1b    = (const float*)d_in[11];
    const float* ln2g    = (const float*)d_in[12];
    const float* ln2b    = (const float*)d_in[13];
    const float* W1      = (const float*)d_in[14];
    const float* b1      = (const float*)d_in[15];
    const float* W2      = (const float*)d_in[16];
    const float* b2      = (const float*)d_in[17];
    const float* Wh      = (const float*)d_in[18];
    const float* bh      = (const float*)d_in[19];
    float* out = (float*)d_out;

    float* x = (float*)d_ws;
    unsigned short* h_bf   = (unsigned short*)(x + (size_t)NTOK * DD);
    unsigned short* q_bf   = h_bf + (size_t)MPAD * DD;
    unsigned short* k_bf   = q_bf + (size_t)MPAD * DD;
    unsigned short* v_bf   = k_bf + (size_t)MPAD * DD;
    unsigned short* mlp_bf = v_bf + (size_t)MPAD * DD;            // MPAD*FF
    unsigned short* W1_bf  = mlp_bf + (size_t)MPAD * FF;
    unsigned short* W2_bf  = W1_bf + (size_t)FF * DD;
    unsigned short* We_bf  = W2_bf + (size_t)FF * DD;
    unsigned short* Wq_bf  = We_bf + (size_t)DD * DD;             // L*H*64*64
    unsigned short* Wk_bf  = Wq_bf + (size_t)LL * HH * DHD * DHD;
    unsigned short* Wv_bf  = Wk_bf + (size_t)LL * HH * DHD * DHD;
    unsigned short* P_bf   = mlp_bf;                              // alias pre-loop

    const int QKVW = LL * HH * DHD * DHD;                         // 589824

    // one-time weight conversions
    k_conv<<<576, 256, 0, stream>>>(W_embed, We_bf, DD * DD / 4);
    k_conv<<<576, 256, 0, stream>>>(Wq, Wq_bf, QKVW / 4);
    k_conv<<<576, 256, 0, stream>>>(Wk, Wk_bf, QKVW / 4);
    k_conv<<<576, 256, 0, stream>>>(Wv, Wv_bf, QKVW / 4);

    // embed
    k_patchify<<<1024, 256, 0, stream>>>(image, P_bf);
    k_gemm_bf<0><<<dim3(6, 49), 256, 0, stream>>>(P_bf, We_bf, b_embed, x,
                                                  BB * NPATCH, DD, DD);
    k_posadd<<<1024, 256, 0, stream>>>(x, cls);

    for (int l = 0; l < LL; ++l) {
        k_ln2<<<(NTOK + 3) / 4, 256, 0, stream>>>(x, ln1g + l * DD, ln1b + l * DD, h_bf);
        k_qkv_mfma<<<dim3(HH, MPAD / 128), 256, 0, stream>>>(
            h_bf, Wq_bf + (size_t)l * HH * 4096, Wk_bf + (size_t)l * HH * 4096,
            Wv_bf + (size_t)l * HH * 4096, bq + l * DD, bk + l * DD, bv + l * DD,
            q_bf, k_bf, v_bf);
        k_attn3<<<dim3(4, HH, BB), 256, 0, stream>>>(q_bf, k_bf, v_bf, x);
        k_ln2<<<(NTOK + 3) / 4, 256, 0, stream>>>(x, ln2g + l * DD, ln2b + l * DD, h_bf);
        k_conv2<<<2048, 256, 0, stream>>>(W1 + (size_t)l * FF * DD, W1_bf, FF * DD / 4,
                                          W2 + (size_t)l * DD * FF, W2_bf, FF * DD / 4);
        k_gemm_bf<1><<<dim3(FF / 128, MPAD / 128), 256, 0, stream>>>(
            h_bf, W1_bf, b1 + (size_t)l * FF, mlp_bf, NTOK, FF, DD);
        k_gemm_w2<<<dim3(DD / 64, MPAD / 128), 256, 0, stream>>>(
            mlp_bf, W2_bf, b2 + (size_t)l * DD, x, NTOK, FF);
    }

    k_head<<<dim3(4, BB), 256, 0, stream>>>(x, Wh, bh, out);
}

// Round 7
// 2739.704 us; speedup vs baseline: 1.0063x; 1.0063x over previous
//
#include <hip/hip_runtime.h>
#include <math.h>

// R7: compose best measured variant per GEMM.
//  R6 post-mortem arithmetic (non-GEMM kernels identical R5 vs R6):
//    bf1: dbuf 99us -> simple <74us  (dbuf HURTS short K=768, 24 steps)
//    w2:  dbuf ~45-50us -> simple 74.3us (dbuf HELPS long K=3072, 96 steps —
//         prologue amortized, vmcnt(3) hides per-step load latency)
//  => bf1 stays simple (R6), w2 goes back to R5's dbuf version verbatim.
//  Keep: XCD swizzle, chunk-XOR LDS swizzle (0 bank conflicts), non-atomic w2.

// ---- problem constants ----
#define BB 32
#define SS 197
#define DD 768
#define HH 12
#define DHD 64
#define LL 12
#define FF 3072
#define NPATCH 196
#define NTOK (BB * SS)          // 6304
#define MPAD 6400               // NTOK padded to multiple of 128
#define LNEPS 1e-5f

typedef short bf8_t __attribute__((ext_vector_type(8)));
typedef float f4_t  __attribute__((ext_vector_type(4)));
typedef unsigned short u16x8 __attribute__((ext_vector_type(8)));

__device__ __forceinline__ unsigned short f2bf(float x) {
    unsigned u = __float_as_uint(x);
    return (unsigned short)((u + 0x8000u) >> 16);
}
__device__ __forceinline__ float bf_lo(unsigned u) { return __uint_as_float(u << 16); }

__device__ __forceinline__ void gl_lds16(const void* g, void* l) {
    __builtin_amdgcn_global_load_lds((const __attribute__((address_space(1))) unsigned int*)g,
                                     (__attribute__((address_space(3))) unsigned int*)l, 16, 0, 0);
}

// bijective XCD-aware block swizzle (m204 variant; works for any nwg)
__device__ __forceinline__ int xcd_swz(int bid, int nwg) {
    const int q = nwg >> 3, r = nwg & 7;
    const int xcd = bid & 7, idx = bid >> 3;
    return (xcd < r ? xcd * (q + 1) : r * (q + 1) + (xcd - r) * q) + idx;
}

// =====================================================================
// fp32 -> bf16 converters
// =====================================================================
__global__ __launch_bounds__(256) void k_conv(const float* __restrict__ a,
                                              unsigned short* __restrict__ o, int n4) {
    for (int i = blockIdx.x * 256 + threadIdx.x; i < n4; i += gridDim.x * 256) {
        float4 v = ((const float4*)a)[i];
        ushort4 r;
        r.x = f2bf(v.x); r.y = f2bf(v.y); r.z = f2bf(v.z); r.w = f2bf(v.w);
        ((ushort4*)o)[i] = r;
    }
}

// two tensors in one launch (per-layer W1+W2)
__global__ __launch_bounds__(256) void k_conv2(const float* __restrict__ a1,
                                               unsigned short* __restrict__ o1, int n1,
                                               const float* __restrict__ a2,
                                               unsigned short* __restrict__ o2, int n2) {
    for (int i = blockIdx.x * 256 + threadIdx.x; i < n1 + n2; i += gridDim.x * 256) {
        const float* a = (i < n1) ? a1 : a2;
        unsigned short* o = (i < n1) ? o1 : o2;
        int j = (i < n1) ? i : i - n1;
        float4 v = ((const float4*)a)[j];
        ushort4 r;
        r.x = f2bf(v.x); r.y = f2bf(v.y); r.z = f2bf(v.z); r.w = f2bf(v.w);
        ((ushort4*)o)[j] = r;
    }
}

// =====================================================================
// patchify: image [B,3,224,224] -> P_bf [B*196, 768] bf16, order (c,pi,pj)
// =====================================================================
__global__ __launch_bounds__(256) void k_patchify(const float* __restrict__ img,
                                                  unsigned short* __restrict__ P) {
    const int total = BB * NPATCH * DD;
    for (int idx = blockIdx.x * 256 + threadIdx.x; idx < total; idx += gridDim.x * 256) {
        int e = idx % DD;
        int rest = idx / DD;
        int p = rest % NPATCH;
        int b = rest / NPATCH;
        int c = e >> 8;
        int pi = (e >> 4) & 15;
        int pj = e & 15;
        int i = p / 14, j = p % 14;
        P[idx] = f2bf(img[(((size_t)b * 3 + c) * 224 + (i * 16 + pi)) * 224 + (j * 16 + pj)]);
    }
}

// =====================================================================
// bf16 MFMA GEMM (m97 simple structure): C[m,n] = A[m,k] * W[n,k]^T + bias
// EPI: 0 = embed (remap rows, f32 store), 1 = GELU -> bf16, 2 = res add f32
// =====================================================================
template <int EPI>
__global__ __launch_bounds__(256) void k_gemm_bf(const unsigned short* __restrict__ A,
                                                 const unsigned short* __restrict__ Bw,
                                                 const float* __restrict__ bias,
                                                 void* __restrict__ Cout,
                                                 int M, int N, int K) {
    __shared__ unsigned short As[128 * 32];
    __shared__ unsigned short Bs[128 * 32];
    const int tid = threadIdx.x;
    const int wave = tid >> 6, lane = tid & 63;

    const int nwg = gridDim.x * gridDim.y;
    const int sb = xcd_swz(blockIdx.y * gridDim.x + blockIdx.x, nwg);
    const int bx = sb % gridDim.x, by = sb / gridDim.x;
    const int m0 = by << 7, n0 = bx << 7;

    const int r0 = tid >> 2;
    const int kp = (((tid & 3) ^ ((r0 >> 1) & 3)) << 3);   // pre-swizzled source chunk
    const unsigned short* gA0 = A + (size_t)(m0 + r0) * K + kp;
    const unsigned short* gA1 = A + (size_t)(m0 + 64 + r0) * K + kp;
    const unsigned short* gB0 = Bw + (size_t)(n0 + r0) * K + kp;
    const unsigned short* gB1 = Bw + (size_t)(n0 + 64 + r0) * K + kp;
    unsigned short* lA0 = &As[tid * 8];
    unsigned short* lA1 = &As[(tid + 256) * 8];
    unsigned short* lB0 = &Bs[tid * 8];
    unsigned short* lB1 = &Bs[(tid + 256) * 8];

    const int mh = (wave >> 1) << 6, nh = (wave & 1) << 6;
    const int lm = lane & 15, kq = lane >> 4;
    const int kqx = ((kq ^ ((lm >> 1) & 3)) << 3);         // swizzled read chunk (shorts)

    f4_t acc[4][4];
#pragma unroll
    for (int i = 0; i < 4; ++i)
#pragma unroll
        for (int j = 0; j < 4; ++j) acc[i][j] = (f4_t){0.f, 0.f, 0.f, 0.f};

    for (int k0 = 0; k0 < K; k0 += 32) {
        gl_lds16(gA0, lA0);
        gl_lds16(gA1, lA1);
        gl_lds16(gB0, lB0);
        gl_lds16(gB1, lB1);
        gA0 += 32; gA1 += 32; gB0 += 32; gB1 += 32;
        __syncthreads();
        bf8_t af[4], bfr[4];
#pragma unroll
        for (int mt = 0; mt < 4; ++mt)
            af[mt] = *(const bf8_t*)&As[(mh + mt * 16 + lm) * 32 + kqx];
#pragma unroll
        for (int nv = 0; nv < 4; ++nv)
            bfr[nv] = *(const bf8_t*)&Bs[(nh + nv * 16 + lm) * 32 + kqx];
#pragma unroll
        for (int mt = 0; mt < 4; ++mt)
#pragma unroll
            for (int nv = 0; nv < 4; ++nv)
                acc[mt][nv] = __builtin_amdgcn_mfma_f32_16x16x32_bf16(af[mt], bfr[nv],
                                                                      acc[mt][nv], 0, 0, 0);
        __syncthreads();
    }

    const int rbase = m0 + mh + kq * 4;
    const int cbase = n0 + nh + lm;
#pragma unroll
    for (int mt = 0; mt < 4; ++mt) {
#pragma unroll
        for (int nv = 0; nv < 4; ++nv) {
            const int col = cbase + nv * 16;
            const float bv = bias[col];
#pragma unroll
            for (int r = 0; r < 4; ++r) {
                const int row = rbase + mt * 16 + r;
                float val = acc[mt][nv][r] + bv;
                if (EPI == 0) {
                    size_t om = (size_t)(row / 196) * 197 + (row % 196) + 1;
                    ((float*)Cout)[om * DD + col] = val;
                } else if (EPI == 1) {
                    val = 0.5f * val * (1.f + erff(val * 0.7071067811865476f));
                    ((unsigned short*)Cout)[(size_t)row * N + col] = f2bf(val);
                } else {
                    if (row < M) ((float*)Cout)[(size_t)row * DD + col] += val;
                }
            }
        }
    }
}

// =====================================================================
// W2 GEMM, no split-K, 128x64 tile, dbuf 2-phase (R5 version — measured
// ~45-50us vs 74us simple; K=3072's 96 steps amortize the pipeline):
// x[m, n] += A[m,k] * W2[n,k]^T + bias.  grid (12, 50) = 600 blocks;
// one owner per output element -> plain RMW epilogue (no atomics).
// Wave layout: 2M x 2N, each wave 64x32 -> acc[4][2].
// =====================================================================
__global__ __launch_bounds__(256) void k_gemm_w2(const unsigned short* __restrict__ A,
                                                 const unsigned short* __restrict__ Bw,
                                                 const float* __restrict__ bias,
                                                 float* __restrict__ x,
                                                 int M, int K) {
    __shared__ unsigned short As[2][128 * 32];
    __shared__ unsigned short Bs[2][64 * 32];
    const int tid = threadIdx.x;
    const int wave = tid >> 6, lane = tid & 63;

    const int nwg = gridDim.x * gridDim.y;   // 600
    const int sb = xcd_swz(blockIdx.y * gridDim.x + blockIdx.x, nwg);
    const int bx = sb % gridDim.x, by = sb / gridDim.x;
    const int m0 = by << 7, n0 = bx << 6;

    const int r0 = tid >> 2;
    const int kp = (((tid & 3) ^ ((r0 >> 1) & 3)) << 3);   // pre-swizzled source chunk
    const unsigned short* gA0 = A + (size_t)(m0 + r0) * K + kp;
    const unsigned short* gA1 = A + (size_t)(m0 + 64 + r0) * K + kp;
    const unsigned short* gB0 = Bw + (size_t)(n0 + r0) * K + kp;

    const int mh = (wave >> 1) << 6, nh = (wave & 1) << 5;
    const int lm = lane & 15, kq = lane >> 4;
    const int kqx = ((kq ^ ((lm >> 1) & 3)) << 3);

    f4_t acc[4][2];
#pragma unroll
    for (int i = 0; i < 4; ++i)
#pragma unroll
        for (int j = 0; j < 2; ++j) acc[i][j] = (f4_t){0.f, 0.f, 0.f, 0.f};

    const int nt = K >> 5;   // 96
    gl_lds16(gA0, &As[0][tid * 8]);
    gl_lds16(gA1, &As[0][(tid + 256) * 8]);
    gl_lds16(gB0, &Bs[0][tid * 8]);
    gA0 += 32; gA1 += 32; gB0 += 32;

    for (int t = 0; t < nt; ++t) {
        const int cur = t & 1;
        if (t + 1 < nt) {
            const int nxb = cur ^ 1;
            gl_lds16(gA0, &As[nxb][tid * 8]);
            gl_lds16(gA1, &As[nxb][(tid + 256) * 8]);
            gl_lds16(gB0, &Bs[nxb][tid * 8]);
            gA0 += 32; gA1 += 32; gB0 += 32;
            asm volatile("s_waitcnt vmcnt(3)" ::: "memory");   // tile t landed, t+1 in flight
        } else {
            asm volatile("s_waitcnt vmcnt(0)" ::: "memory");
        }
        __builtin_amdgcn_s_barrier();
        __builtin_amdgcn_sched_barrier(0);
        bf8_t af[4], bfr[2];
#pragma unroll
        for (int mt = 0; mt < 4; ++mt)
            af[mt] = *(const bf8_t*)&As[cur][(mh + mt * 16 + lm) * 32 + kqx];
#pragma unroll
        for (int nv = 0; nv < 2; ++nv)
            bfr[nv] = *(const bf8_t*)&Bs[cur][(nh + nv * 16 + lm) * 32 + kqx];
#pragma unroll
        for (int mt = 0; mt < 4; ++mt)
#pragma unroll
            for (int nv = 0; nv < 2; ++nv)
                acc[mt][nv] = __builtin_amdgcn_mfma_f32_16x16x32_bf16(af[mt], bfr[nv],
                                                                      acc[mt][nv], 0, 0, 0);
        asm volatile("s_waitcnt lgkmcnt(0)" ::: "memory");
        __builtin_amdgcn_sched_barrier(0);
        __builtin_amdgcn_s_barrier();
    }

    const int rbase = m0 + mh + kq * 4;
    const int cbase = n0 + nh + lm;
#pragma unroll
    for (int mt = 0; mt < 4; ++mt) {
#pragma unroll
        for (int nv = 0; nv < 2; ++nv) {
            const int col = cbase + nv * 16;
            const float bv = bias[col];
#pragma unroll
            for (int r = 0; r < 4; ++r) {
                const int row = rbase + mt * 16 + r;
                if (row < M)
                    x[(size_t)row * DD + col] += acc[mt][nv][r] + bv;
            }
        }
    }
}

// =====================================================================
// QKV via MFMA: block = (head, 128-token tile). Single-barrier K=64.
// =====================================================================
__global__ __launch_bounds__(256) void k_qkv_mfma(const unsigned short* __restrict__ h,
                                                  const unsigned short* __restrict__ Wqb,
                                                  const unsigned short* __restrict__ Wkb,
                                                  const unsigned short* __restrict__ Wvb,
                                                  const float* __restrict__ bq,
                                                  const float* __restrict__ bk,
                                                  const float* __restrict__ bv,
                                                  unsigned short* __restrict__ qo,
                                                  unsigned short* __restrict__ ko,
                                                  unsigned short* __restrict__ vo) {
    __shared__ unsigned short As[2 * 128 * 32];       // [khalf][row][32]
    __shared__ unsigned short Bs[3 * 2 * 64 * 32];    // [mat][khalf][row][32]
    const int head = blockIdx.x;
    const int m0 = blockIdx.y << 7;
    const int tid = threadIdx.x;
    const int wave = tid >> 6, lane = tid & 63;
    const int lm = lane & 15, kq = lane >> 4;

#pragma unroll
    for (int j = 0; j < 4; ++j) {
        int khalf = j >> 1;
        int rem = (j & 1) * 256 + tid;           // 0..511
        int row = rem >> 2, koff = (rem & 3) * 8;
        gl_lds16(h + (size_t)(m0 + row) * DD + head * 64 + khalf * 32 + koff,
                 &As[(j * 256 + tid) * 8]);
    }
    const unsigned short* Wq_h = Wqb + head * 4096;
    const unsigned short* Wk_h = Wkb + head * 4096;
    const unsigned short* Wv_h = Wvb + head * 4096;
#pragma unroll
    for (int j = 0; j < 6; ++j) {
        const unsigned short* src = (j < 2) ? Wq_h : ((j < 4) ? Wk_h : Wv_h);
        int cm = (j & 1) * 256 + tid;            // 0..511 within mat
        int khalf = cm >> 8;
        int rem2 = cm & 255;
        int row = rem2 >> 2, koff = (rem2 & 3) * 8;
        gl_lds16(src + row * 64 + khalf * 32 + koff, &Bs[(j * 256 + tid) * 8]);
    }
    __syncthreads();

    f4_t acc[2][12];
#pragma unroll
    for (int i = 0; i < 2; ++i)
#pragma unroll
        for (int j = 0; j < 12; ++j) acc[i][j] = (f4_t){0.f, 0.f, 0.f, 0.f};

#pragma unroll
    for (int kh = 0; kh < 2; ++kh) {
        bf8_t af[2], bfr[12];
#pragma unroll
        for (int mt = 0; mt < 2; ++mt)
            af[mt] = *(const bf8_t*)&As[kh * 4096 + (wave * 32 + mt * 16 + lm) * 32 + kq * 8];
#pragma unroll
        for (int nt = 0; nt < 12; ++nt)
            bfr[nt] = *(const bf8_t*)&Bs[(nt >> 2) * 4096 + kh * 2048 +
                                         ((nt & 3) * 16 + lm) * 32 + kq * 8];
#pragma unroll
        for (int mt = 0; mt < 2; ++mt)
#pragma unroll
            for (int nt = 0; nt < 12; ++nt)
                acc[mt][nt] = __builtin_amdgcn_mfma_f32_16x16x32_bf16(af[mt], bfr[nt],
                                                                      acc[mt][nt], 0, 0, 0);
    }

    const int rbase = m0 + wave * 32 + kq * 4;
#pragma unroll
    for (int mt = 0; mt < 2; ++mt) {
#pragma unroll
        for (int nt = 0; nt < 12; ++nt) {
            const int col = nt * 16 + lm;
            const int e = col & 63;
            const float* bsrc = (nt < 4) ? bq : ((nt < 8) ? bk : bv);
            unsigned short* dst = (nt < 4) ? qo : ((nt < 8) ? ko : vo);
            const float bval = bsrc[head * 64 + e];
#pragma unroll
            for (int r = 0; r < 4; ++r) {
                const int row = rbase + mt * 16 + r;
                if (row < NTOK)
                    dst[(size_t)row * DD + head * 64 + e] = f2bf(acc[mt][nt][r] + bval);
            }
        }
    }
}

// =====================================================================
// pos-embed add (+cls for s==0)
// =====================================================================
__global__ __launch_bounds__(256) void k_posadd(float* __restrict__ x,
                                                const float* __restrict__ cls) {
    const int total = BB * SS * DD;
    const float LN1E4 = 9.210340371976184f;
    for (int idx = blockIdx.x * 256 + threadIdx.x; idx < total; idx += gridDim.x * 256) {
        int d = idx % DD;
        int s = (idx / DD) % SS;
        float ang = (float)s * __expf(-LN1E4 * (float)(2 * (d >> 1)) / 768.f);
        float pv = (d & 1) ? __cosf(ang) : __sinf(ang);
        if (s == 0) x[idx] = cls[d] + pv;
        else        x[idx] += pv;
    }
}

// =====================================================================
// LayerNorm: wave per row (4 rows/block), lane holds 12 elems, bf16 out
// =====================================================================
__global__ __launch_bounds__(256) void k_ln2(const float* __restrict__ x,
                                             const float* __restrict__ g,
                                             const float* __restrict__ bp,
                                             unsigned short* __restrict__ out) {
    const int row = blockIdx.x * 4 + (threadIdx.x >> 6);
    const int lane = threadIdx.x & 63;
    if (row >= NTOK) return;
    const float* xr = x + (size_t)row * DD + lane * 12;
    float4 a = ((const float4*)xr)[0];
    float4 b = ((const float4*)xr)[1];
    float4 c = ((const float4*)xr)[2];
    float s = a.x + a.y + a.z + a.w + b.x + b.y + b.z + b.w + c.x + c.y + c.z + c.w;
#pragma unroll
    for (int o = 32; o; o >>= 1) s += __shfl_xor(s, o);
    const float mean = s * (1.f / DD);
    float vr = 0.f, e0;
    e0 = a.x - mean; vr += e0 * e0; e0 = a.y - mean; vr += e0 * e0;
    e0 = a.z - mean; vr += e0 * e0; e0 = a.w - mean; vr += e0 * e0;
    e0 = b.x - mean; vr += e0 * e0; e0 = b.y - mean; vr += e0 * e0;
    e0 = b.z - mean; vr += e0 * e0; e0 = b.w - mean; vr += e0 * e0;
    e0 = c.x - mean; vr += e0 * e0; e0 = c.y - mean; vr += e0 * e0;
    e0 = c.z - mean; vr += e0 * e0; e0 = c.w - mean; vr += e0 * e0;
#pragma unroll
    for (int o = 32; o; o >>= 1) vr += __shfl_xor(vr, o);
    const float rstd = rsqrtf(vr * (1.f / DD) + LNEPS);

    const float4* g4 = (const float4*)(g + lane * 12);
    const float4* b4p = (const float4*)(bp + lane * 12);
    unsigned short* op = out + (size_t)row * DD + lane * 12;
    float4 gv, bv;
    ushort4 r;
    gv = g4[0]; bv = b4p[0];
    r.x = f2bf((a.x - mean) * rstd * gv.x + bv.x);
    r.y = f2bf((a.y - mean) * rstd * gv.y + bv.y);
    r.z = f2bf((a.z - mean) * rstd * gv.z + bv.z);
    r.w = f2bf((a.w - mean) * rstd * gv.w + bv.w);
    ((ushort4*)op)[0] = r;
    gv = g4[1]; bv = b4p[1];
    r.x = f2bf((b.x - mean) * rstd * gv.x + bv.x);
    r.y = f2bf((b.y - mean) * rstd * gv.y + bv.y);
    r.z = f2bf((b.z - mean) * rstd * gv.z + bv.z);
    r.w = f2bf((b.w - mean) * rstd * gv.w + bv.w);
    ((ushort4*)op)[1] = r;
    gv = g4[2]; bv = b4p[2];
    r.x = f2bf((c.x - mean) * rstd * gv.x + bv.x);
    r.y = f2bf((c.y - mean) * rstd * gv.y + bv.y);
    r.z = f2bf((c.z - mean) * rstd * gv.z + bv.z);
    r.w = f2bf((c.w - mean) * rstd * gv.w + bv.w);
    ((ushort4*)op)[2] = r;
}

// =====================================================================
// attention v3 (MFMA): block = (64-query tile, head, b), 256 thr = 4 waves.
// =====================================================================
__global__ __launch_bounds__(256) void k_attn3(const unsigned short* __restrict__ qg,
                                               const unsigned short* __restrict__ kg,
                                               const unsigned short* __restrict__ vg,
                                               float* __restrict__ x) {
    const int qt = blockIdx.x, head = blockIdx.y, b = blockIdx.z;
    const int tid = threadIdx.x, wv = tid >> 6, lane = tid & 63;
    const int lm = lane & 15, kq = lane >> 4;

    __shared__ __align__(16) unsigned short lds[29696];   // 59392 B
    unsigned short* Kl = lds;            // [kh][224][32] = 14336 sh
    unsigned short* Pl = lds;            // [4][16][232]  = 14848 sh (aliases K)
    unsigned short* Vt = lds + 14848;    // [64][232]     = 14848 sh

    const size_t tokbase = (size_t)b * SS;
    const unsigned short* kb = kg + tokbase * DD + head * 64;
    const unsigned short* vb = vg + tokbase * DD + head * 64;
    const unsigned short* qb = qg + tokbase * DD + head * 64;

    // ---- stage K: [kh][t(224)][32], 1792 x 16B chunks via global_load_lds ----
#pragma unroll
    for (int it = 0; it < 7; ++it) {
        int c = it * 256 + tid;
        int kh = c / 896, rem = c - kh * 896;
        int t = rem >> 2, cc = rem & 3;
        gl_lds16(kb + (size_t)t * DD + kh * 32 + cc * 8, (char*)lds + c * 16);
    }
    // ---- stage V transposed: Vt[e][t], t padded 224 (197.. zeroed) ----
#pragma unroll
    for (int it = 0; it < 7; ++it) {
        int idx = it * 256 + tid;
        int t = idx >> 3, eg = idx & 7;
        if (t < SS) {
            u16x8 v8 = *(const u16x8*)(vb + (size_t)t * DD + eg * 8);
#pragma unroll
            for (int j = 0; j < 8; ++j) Vt[(eg * 8 + j) * 232 + t] = v8[j];
        } else {
#pragma unroll
            for (int j = 0; j < 8; ++j) Vt[(eg * 8 + j) * 232 + t] = 0;
        }
    }

    // ---- Q fragments (B-operand) straight from global ----
    const int qrow = qt * 64 + wv * 16 + lm;
    bf8_t qf0 = *(const bf8_t*)(qb + (size_t)qrow * DD + kq * 8);
    bf8_t qf1 = *(const bf8_t*)(qb + (size_t)qrow * DD + 32 + kq * 8);

    __syncthreads();

    // ---- S^T: D[t-tile][q16] ; 13 t-tiles x 2 kh ----
    f4_t sacc[13];
#pragma unroll
    for (int tt = 0; tt < 13; ++tt) sacc[tt] = (f4_t){0.f, 0.f, 0.f, 0.f};
#pragma unroll
    for (int tt = 0; tt < 13; ++tt) {
        bf8_t a0 = *(const bf8_t*)&Kl[(tt * 16 + lm) * 32 + kq * 8];
        bf8_t a1 = *(const bf8_t*)&Kl[7168 + (tt * 16 + lm) * 32 + kq * 8];
        sacc[tt] = __builtin_amdgcn_mfma_f32_16x16x32_bf16(a0, qf0, sacc[tt], 0, 0, 0);
        sacc[tt] = __builtin_amdgcn_mfma_f32_16x16x32_bf16(a1, qf1, sacc[tt], 0, 0, 0);
    }

    // ---- softmax over t for q = lm ----
    float mx = -1e30f;
#pragma unroll
    for (int tt = 0; tt < 13; ++tt)
#pragma unroll
        for (int r = 0; r < 4; ++r) {
            float s = sacc[tt][r] * 0.125f;
            if (tt == 12 && (kq * 4 + r) >= 5) s = -1e30f;   // t >= 197
            sacc[tt][r] = s;
            mx = fmaxf(mx, s);
        }
    mx = fmaxf(mx, __shfl_xor(mx, 16));
    mx = fmaxf(mx, __shfl_xor(mx, 32));
    float sum = 0.f;
#pragma unroll
    for (int tt = 0; tt < 13; ++tt)
#pragma unroll
        for (int r = 0; r < 4; ++r) {
            float p = __expf(sacc[tt][r] - mx);
            sacc[tt][r] = p;
            sum += p;
        }
    sum += __shfl_xor(sum, 16);
    sum += __shfl_xor(sum, 32);
    const float inv = 1.f / sum;

    __syncthreads();   // all waves done reading K -> safe to overwrite with P

    // ---- write P (A-layout rows [q][t], per-wave region) ----
    unsigned short* Pw = Pl + wv * 3712;
#pragma unroll
    for (int tt = 0; tt < 13; ++tt)
#pragma unroll
        for (int r = 0; r < 4; ++r)
            Pw[lm * 232 + tt * 16 + kq * 4 + r] = f2bf(sacc[tt][r]);
    *(short4*)&Pw[lm * 232 + 208 + kq * 4] = make_short4(0, 0, 0, 0);

    // ---- PV: O[q][e] ; 7 k-chunks x 4 e-tiles ----
    f4_t oacc[4];
#pragma unroll
    for (int et = 0; et < 4; ++et) oacc[et] = (f4_t){0.f, 0.f, 0.f, 0.f};
#pragma unroll
    for (int kc = 0; kc < 7; ++kc) {
        bf8_t pa = *(const bf8_t*)&Pw[lm * 232 + kc * 32 + kq * 8];
#pragma unroll
        for (int et = 0; et < 4; ++et) {
            bf8_t vv = *(const bf8_t*)&Vt[(et * 16 + lm) * 232 + kc * 32 + kq * 8];
            oacc[et] = __builtin_amdgcn_mfma_f32_16x16x32_bf16(pa, vv, oacc[et], 0, 0, 0);
        }
    }

    // ---- 1/sum redistribution (softmax layout q=lm -> C layout q=kq*4+r) ----
    float invq[4];
#pragma unroll
    for (int r = 0; r < 4; ++r) invq[r] = __shfl(inv, kq * 4 + r);

    // ---- residual add into x ----
    float* xp = x + tokbase * DD + head * 64;
#pragma unroll
    for (int r = 0; r < 4; ++r) {
        const int qgr = qt * 64 + wv * 16 + kq * 4 + r;
        if (qgr < SS) {
#pragma unroll
            for (int et = 0; et < 4; ++et)
                xp[(size_t)qgr * DD + et * 16 + lm] += oacc[et][r] * invq[r];
        }
    }
}

// =====================================================================
// classifier head (fp32)
// =====================================================================
__global__ __launch_bounds__(256) void k_head(const float* __restrict__ x,
                                              const float* __restrict__ Wh,
                                              const float* __restrict__ bh,
                                              float* __restrict__ out) {
    const int b = blockIdx.y;
    const int c = blockIdx.x * 256 + threadIdx.x;
    __shared__ __align__(16) float xs[DD];
    const float* xr = x + (size_t)b * SS * DD;
    for (int d = threadIdx.x; d < DD; d += 256) xs[d] = xr[d];
    __syncthreads();
    if (c < 1000) {
        const float4* w4 = (const float4*)(Wh + (size_t)c * DD);
        float acc = 0.f;
#pragma unroll 4
        for (int d4 = 0; d4 < DD / 4; ++d4) {
            float4 w = w4[d4];
            const float4 xv = *(const float4*)&xs[d4 << 2];
            acc += xv.x * w.x + xv.y * w.y + xv.z * w.z + xv.w * w.w;
        }
        out[(size_t)b * 1000 + c] = acc + bh[c];
    }
}

// =====================================================================
extern "C" void kernel_launch(void* const* d_in, const int* in_sizes, int n_in,
                              void* d_out, int out_size, void* d_ws, size_t ws_size,
                              hipStream_t stream) {
    const float* image   = (const float*)d_in[0];
    const float* W_embed = (const float*)d_in[1];
    const float* b_embed = (const float*)d_in[2];
    const float* cls     = (const float*)d_in[3];
    const float* Wq      = (const float*)d_in[4];
    const float* bq      = (const float*)d_in[5];
    const float* Wk      = (const float*)d_in[6];
    const float* bk      = (const float*)d_in[7];
    const float* Wv      = (const float*)d_in[8];
    const float* bv      = (const float*)d_in[9];
    const float* ln1g    = (const float*)d_in[10];
    const float* ln1b    = (const float*)d_in[11];
    const float* ln2g    = (const float*)d_in[12];
    const float* ln2b    = (const float*)d_in[13];
    const float* W1      = (const float*)d_in[14];
    const float* b1      = (const float*)d_in[15];
    const float* W2      = (const float*)d_in[16];
    const float* b2      = (const float*)d_in[17];
    const float* Wh      = (const float*)d_in[18];
    const float* bh      = (const float*)d_in[19];
    float* out = (float*)d_out;

    float* x = (float*)d_ws;
    unsigned short* h_bf   = (unsigned short*)(x + (size_t)NTOK * DD);
    unsigned short* q_bf   = h_bf + (size_t)MPAD * DD;
    unsigned short* k_bf   = q_bf + (size_t)MPAD * DD;
    unsigned short* v_bf   = k_bf + (size_t)MPAD * DD;
    unsigned short* mlp_bf = v_bf + (size_t)MPAD * DD;            // MPAD*FF
    unsigned short* W1_bf  = mlp_bf + (size_t)MPAD * FF;
    unsigned short* W2_bf  = W1_bf + (size_t)FF * DD;
    unsigned short* We_bf  = W2_bf + (size_t)FF * DD;
    unsigned short* Wq_bf  = We_bf + (size_t)DD * DD;             // L*H*64*64
    unsigned short* Wk_bf  = Wq_bf + (size_t)LL * HH * DHD * DHD;
    unsigned short* Wv_bf  = Wk_bf + (size_t)LL * HH * DHD * DHD;
    unsigned short* P_bf   = mlp_bf;                              // alias pre-loop

    const int QKVW = LL * HH * DHD * DHD;                         // 589824

    // one-time weight conversions
    k_conv<<<576, 256, 0, stream>>>(W_embed, We_bf, DD * DD / 4);
    k_conv<<<576, 256, 0, stream>>>(Wq, Wq_bf, QKVW / 4);
    k_conv<<<576, 256, 0, stream>>>(Wk, Wk_bf, QKVW / 4);
    k_conv<<<576, 256, 0, stream>>>(Wv, Wv_bf, QKVW / 4);

    // embed
    k_patchify<<<1024, 256, 0, stream>>>(image, P_bf);
    k_gemm_bf<0><<<dim3(6, 49), 256, 0, stream>>>(P_bf, We_bf, b_embed, x,
                                                  BB * NPATCH, DD, DD);
    k_posadd<<<1024, 256, 0, stream>>>(x, cls);

    for (int l = 0; l < LL; ++l) {
        k_ln2<<<(NTOK + 3) / 4, 256, 0, stream>>>(x, ln1g + l * DD, ln1b + l * DD, h_bf);
        k_qkv_mfma<<<dim3(HH, MPAD / 128), 256, 0, stream>>>(
            h_bf, Wq_bf + (size_t)l * HH * 4096, Wk_bf + (size_t)l * HH * 4096,
            Wv_bf + (size_t)l * HH * 4096, bq + l * DD, bk + l * DD, bv + l * DD,
            q_bf, k_bf, v_bf);
        k_attn3<<<dim3(4, HH, BB), 256, 0, stream>>>(q_bf, k_bf, v_bf, x);
        k_ln2<<<(NTOK + 3) / 4, 256, 0, stream>>>(x, ln2g + l * DD, ln2b + l * DD, h_bf);
        k_conv2<<<2048, 256, 0, stream>>>(W1 + (size_t)l * FF * DD, W1_bf, FF * DD / 4,
                                          W2 + (size_t)l * DD * FF, W2_bf, FF * DD / 4);
        k_gemm_bf<1><<<dim3(FF / 128, MPAD / 128), 256, 0, stream>>>(
            h_bf, W1_bf, b1 + (size_t)l * FF, mlp_bf, NTOK, FF, DD);
        k_gemm_w2<<<dim3(DD / 64, MPAD / 128), 256, 0, stream>>>(
            mlp_bf, W2_bf, b2 + (size_t)l * DD, x, NTOK, FF);
    }

    k_head<<<dim3(4, BB), 256, 0, stream>>>(x, Wh, bh, out);
}

// Round 9
// 2514.915 us; speedup vs baseline: 1.0963x; 1.0894x over previous
//
#include <hip/hip_runtime.h>
#include <math.h>

// R9 = R8 resubmitted. R8's bench died with "container failed twice" and no
// timing data — the same infra-flake signature as R2/R3 (identical source
// later ran fine as R4). Audit found no hang mechanism in the BK=64 code
// (swizzle involution verified, staging in-bounds, uniform barriers,
// vmcnt(6) matches 6 loads/tile). If this fails again, next round bisects.
//
// R8: BK=32 -> BK=64 on both MLP GEMMs (halve barriers, double MFMA/step).
//  R7 post-mortem: R5/R6/R7 totals within +-1% noise -> dbuf-vs-simple was a
//  wash; both GEMMs are sync-overhead-bound (MfmaUtil 16%, 8-16 MFMA per
//  barrier-pair). BK=64 doubles MFMA-per-barrier WITHOUT changing the sync
//  topology: bf1 simple 32KB LDS, 12 steps x 32 MFMA; w2 dbuf 48KB LDS,
//  48 steps x 16 MFMA, vmcnt(6). Chunk-XOR swizzle extended to 8 chunks/row.

// ---- problem constants ----
#define BB 32
#define SS 197
#define DD 768
#define HH 12
#define DHD 64
#define LL 12
#define FF 3072
#define NPATCH 196
#define NTOK (BB * SS)          // 6304
#define MPAD 6400               // NTOK padded to multiple of 128
#define LNEPS 1e-5f

typedef short bf8_t __attribute__((ext_vector_type(8)));
typedef float f4_t  __attribute__((ext_vector_type(4)));
typedef unsigned short u16x8 __attribute__((ext_vector_type(8)));

__device__ __forceinline__ unsigned short f2bf(float x) {
    unsigned u = __float_as_uint(x);
    return (unsigned short)((u + 0x8000u) >> 16);
}
__device__ __forceinline__ float bf_lo(unsigned u) { return __uint_as_float(u << 16); }

__device__ __forceinline__ void gl_lds16(const void* g, void* l) {
    __builtin_amdgcn_global_load_lds((const __attribute__((address_space(1))) unsigned int*)g,
                                     (__attribute__((address_space(3))) unsigned int*)l, 16, 0, 0);
}

// bijective XCD-aware block swizzle (m204 variant; works for any nwg)
__device__ __forceinline__ int xcd_swz(int bid, int nwg) {
    const int q = nwg >> 3, r = nwg & 7;
    const int xcd = bid & 7, idx = bid >> 3;
    return (xcd < r ? xcd * (q + 1) : r * (q + 1) + (xcd - r) * q) + idx;
}

// =====================================================================
// fp32 -> bf16 converters
// =====================================================================
__global__ __launch_bounds__(256) void k_conv(const float* __restrict__ a,
                                              unsigned short* __restrict__ o, int n4) {
    for (int i = blockIdx.x * 256 + threadIdx.x; i < n4; i += gridDim.x * 256) {
        float4 v = ((const float4*)a)[i];
        ushort4 r;
        r.x = f2bf(v.x); r.y = f2bf(v.y); r.z = f2bf(v.z); r.w = f2bf(v.w);
        ((ushort4*)o)[i] = r;
    }
}

// two tensors in one launch (per-layer W1+W2)
__global__ __launch_bounds__(256) void k_conv2(const float* __restrict__ a1,
                                               unsigned short* __restrict__ o1, int n1,
                                               const float* __restrict__ a2,
                                               unsigned short* __restrict__ o2, int n2) {
    for (int i = blockIdx.x * 256 + threadIdx.x; i < n1 + n2; i += gridDim.x * 256) {
        const float* a = (i < n1) ? a1 : a2;
        unsigned short* o = (i < n1) ? o1 : o2;
        int j = (i < n1) ? i : i - n1;
        float4 v = ((const float4*)a)[j];
        ushort4 r;
        r.x = f2bf(v.x); r.y = f2bf(v.y); r.z = f2bf(v.z); r.w = f2bf(v.w);
        ((ushort4*)o)[j] = r;
    }
}

// =====================================================================
// patchify: image [B,3,224,224] -> P_bf [B*196, 768] bf16, order (c,pi,pj)
// =====================================================================
__global__ __launch_bounds__(256) void k_patchify(const float* __restrict__ img,
                                                  unsigned short* __restrict__ P) {
    const int total = BB * NPATCH * DD;
    for (int idx = blockIdx.x * 256 + threadIdx.x; idx < total; idx += gridDim.x * 256) {
        int e = idx % DD;
        int rest = idx / DD;
        int p = rest % NPATCH;
        int b = rest / NPATCH;
        int c = e >> 8;
        int pi = (e >> 4) & 15;
        int pj = e & 15;
        int i = p / 14, j = p % 14;
        P[idx] = f2bf(img[(((size_t)b * 3 + c) * 224 + (i * 16 + pi)) * 224 + (j * 16 + pj)]);
    }
}

// =====================================================================
// bf16 MFMA GEMM, BK=64, simple sync (m97 topology): C = A * W^T + bias
// EPI: 0 = embed (remap rows, f32 store), 1 = GELU -> bf16, 2 = res add f32
// LDS slot (row, cc) holds global K-chunk cc^(row&7)  (8x16B chunks/row).
// =====================================================================
template <int EPI>
__global__ __launch_bounds__(256) void k_gemm_bf(const unsigned short* __restrict__ A,
                                                 const unsigned short* __restrict__ Bw,
                                                 const float* __restrict__ bias,
                                                 void* __restrict__ Cout,
                                                 int M, int N, int K) {
    __shared__ unsigned short As[128 * 64];   // 16 KB
    __shared__ unsigned short Bs[128 * 64];   // 16 KB
    const int tid = threadIdx.x;
    const int wave = tid >> 6, lane = tid & 63;

    const int nwg = gridDim.x * gridDim.y;
    const int sb = xcd_swz(blockIdx.y * gridDim.x + blockIdx.x, nwg);
    const int bx = sb % gridDim.x, by = sb / gridDim.x;
    const int m0 = by << 7, n0 = bx << 7;

    // staging: 4 chunks/thread each for A and B; chunk c -> row=c>>3, cc=c&7
    const unsigned short* gA[4];
    const unsigned short* gB[4];
#pragma unroll
    for (int it = 0; it < 4; ++it) {
        int c = it * 256 + tid;
        int row = c >> 3, cc = c & 7;
        int csrc = (cc ^ (row & 7)) << 3;     // pre-swizzled source chunk (shorts)
        gA[it] = A + (size_t)(m0 + row) * K + csrc;
        gB[it] = Bw + (size_t)(n0 + row) * K + csrc;
    }

    const int mh = (wave >> 1) << 6, nh = (wave & 1) << 6;
    const int lm = lane & 15, kq = lane >> 4;
    const int l7 = lm & 7;

    f4_t acc[4][4];
#pragma unroll
    for (int i = 0; i < 4; ++i)
#pragma unroll
        for (int j = 0; j < 4; ++j) acc[i][j] = (f4_t){0.f, 0.f, 0.f, 0.f};

    for (int k0 = 0; k0 < K; k0 += 64) {
#pragma unroll
        for (int it = 0; it < 4; ++it) {
            gl_lds16(gA[it], &As[(it * 256 + tid) * 8]);
            gl_lds16(gB[it], &Bs[(it * 256 + tid) * 8]);
            gA[it] += 64; gB[it] += 64;
        }
        __syncthreads();
#pragma unroll
        for (int kk = 0; kk < 2; ++kk) {
            const int jx = ((kk * 4 + kq) ^ l7) << 3;    // swizzled chunk (shorts)
            bf8_t af[4], bfr[4];
#pragma unroll
            for (int mt = 0; mt < 4; ++mt)
                af[mt] = *(const bf8_t*)&As[(mh + mt * 16 + lm) * 64 + jx];
#pragma unroll
            for (int nv = 0; nv < 4; ++nv)
                bfr[nv] = *(const bf8_t*)&Bs[(nh + nv * 16 + lm) * 64 + jx];
#pragma unroll
            for (int mt = 0; mt < 4; ++mt)
#pragma unroll
                for (int nv = 0; nv < 4; ++nv)
                    acc[mt][nv] = __builtin_amdgcn_mfma_f32_16x16x32_bf16(af[mt], bfr[nv],
                                                                          acc[mt][nv], 0, 0, 0);
        }
        __syncthreads();
    }

    const int rbase = m0 + mh + kq * 4;
    const int cbase = n0 + nh + lm;
#pragma unroll
    for (int mt = 0; mt < 4; ++mt) {
#pragma unroll
        for (int nv = 0; nv < 4; ++nv) {
            const int col = cbase + nv * 16;
            const float bv = bias[col];
#pragma unroll
            for (int r = 0; r < 4; ++r) {
                const int row = rbase + mt * 16 + r;
                float val = acc[mt][nv][r] + bv;
                if (EPI == 0) {
                    size_t om = (size_t)(row / 196) * 197 + (row % 196) + 1;
                    ((float*)Cout)[om * DD + col] = val;
                } else if (EPI == 1) {
                    val = 0.5f * val * (1.f + erff(val * 0.7071067811865476f));
                    ((unsigned short*)Cout)[(size_t)row * N + col] = f2bf(val);
                } else {
                    if (row < M) ((float*)Cout)[(size_t)row * DD + col] += val;
                }
            }
        }
    }
}

// =====================================================================
// W2 GEMM, no split-K, 128x64 tile, BK=64, dbuf 2-phase (R5/R7 topology):
// x[m, n] += A[m,k] * W2[n,k]^T + bias.  grid (12, 50) = 600 blocks;
// 48 steps x 16 MFMA/wave; 6 loads/tile -> vmcnt(6).
// =====================================================================
__global__ __launch_bounds__(256) void k_gemm_w2(const unsigned short* __restrict__ A,
                                                 const unsigned short* __restrict__ Bw,
                                                 const float* __restrict__ bias,
                                                 float* __restrict__ x,
                                                 int M, int K) {
    __shared__ unsigned short As[2][128 * 64];   // 2 x 16 KB
    __shared__ unsigned short Bs[2][64 * 64];    // 2 x 8 KB
    const int tid = threadIdx.x;
    const int wave = tid >> 6, lane = tid & 63;

    const int nwg = gridDim.x * gridDim.y;   // 600
    const int sb = xcd_swz(blockIdx.y * gridDim.x + blockIdx.x, nwg);
    const int bx = sb % gridDim.x, by = sb / gridDim.x;
    const int m0 = by << 7, n0 = bx << 6;

    const unsigned short* gA[4];
    const unsigned short* gB[2];
#pragma unroll
    for (int it = 0; it < 4; ++it) {
        int c = it * 256 + tid;
        int row = c >> 3, cc = c & 7;
        gA[it] = A + (size_t)(m0 + row) * K + ((cc ^ (row & 7)) << 3);
    }
#pragma unroll
    for (int it = 0; it < 2; ++it) {
        int c = it * 256 + tid;
        int row = c >> 3, cc = c & 7;
        gB[it] = Bw + (size_t)(n0 + row) * K + ((cc ^ (row & 7)) << 3);
    }

    const int mh = (wave >> 1) << 6, nh = (wave & 1) << 5;
    const int lm = lane & 15, kq = lane >> 4;
    const int l7 = lm & 7;

    f4_t acc[4][2];
#pragma unroll
    for (int i = 0; i < 4; ++i)
#pragma unroll
        for (int j = 0; j < 2; ++j) acc[i][j] = (f4_t){0.f, 0.f, 0.f, 0.f};

    const int nt = K >> 6;   // 48
    // prologue: stage tile 0 into buf 0
#pragma unroll
    for (int it = 0; it < 4; ++it) { gl_lds16(gA[it], &As[0][(it * 256 + tid) * 8]); gA[it] += 64; }
#pragma unroll
    for (int it = 0; it < 2; ++it) { gl_lds16(gB[it], &Bs[0][(it * 256 + tid) * 8]); gB[it] += 64; }

    for (int t = 0; t < nt; ++t) {
        const int cur = t & 1;
        if (t + 1 < nt) {
            const int nxb = cur ^ 1;
#pragma unroll
            for (int it = 0; it < 4; ++it) { gl_lds16(gA[it], &As[nxb][(it * 256 + tid) * 8]); gA[it] += 64; }
#pragma unroll
            for (int it = 0; it < 2; ++it) { gl_lds16(gB[it], &Bs[nxb][(it * 256 + tid) * 8]); gB[it] += 64; }
            asm volatile("s_waitcnt vmcnt(6)" ::: "memory");   // tile t landed, t+1 in flight
        } else {
            asm volatile("s_waitcnt vmcnt(0)" ::: "memory");
        }
        __builtin_amdgcn_s_barrier();
        __builtin_amdgcn_sched_barrier(0);
#pragma unroll
        for (int kk = 0; kk < 2; ++kk) {
            const int jx = ((kk * 4 + kq) ^ l7) << 3;
            bf8_t af[4], bfr[2];
#pragma unroll
            for (int mt = 0; mt < 4; ++mt)
                af[mt] = *(const bf8_t*)&As[cur][(mh + mt * 16 + lm) * 64 + jx];
#pragma unroll
            for (int nv = 0; nv < 2; ++nv)
                bfr[nv] = *(const bf8_t*)&Bs[cur][(nh + nv * 16 + lm) * 64 + jx];
#pragma unroll
            for (int mt = 0; mt < 4; ++mt)
#pragma unroll
                for (int nv = 0; nv < 2; ++nv)
                    acc[mt][nv] = __builtin_amdgcn_mfma_f32_16x16x32_bf16(af[mt], bfr[nv],
                                                                          acc[mt][nv], 0, 0, 0);
        }
        asm volatile("s_waitcnt lgkmcnt(0)" ::: "memory");
        __builtin_amdgcn_sched_barrier(0);
        __builtin_amdgcn_s_barrier();
    }

    const int rbase = m0 + mh + kq * 4;
    const int cbase = n0 + nh + lm;
#pragma unroll
    for (int mt = 0; mt < 4; ++mt) {
#pragma unroll
        for (int nv = 0; nv < 2; ++nv) {
            const int col = cbase + nv * 16;
            const float bv = bias[col];
#pragma unroll
            for (int r = 0; r < 4; ++r) {
                const int row = rbase + mt * 16 + r;
                if (row < M)
                    x[(size_t)row * DD + col] += acc[mt][nv][r] + bv;
            }
        }
    }
}

// =====================================================================
// QKV via MFMA: block = (head, 128-token tile). Single-barrier K=64.
// =====================================================================
__global__ __launch_bounds__(256) void k_qkv_mfma(const unsigned short* __restrict__ h,
                                                  const unsigned short* __restrict__ Wqb,
                                                  const unsigned short* __restrict__ Wkb,
                                                  const unsigned short* __restrict__ Wvb,
                                                  const float* __restrict__ bq,
                                                  const float* __restrict__ bk,
                                                  const float* __restrict__ bv,
                                                  unsigned short* __restrict__ qo,
                                                  unsigned short* __restrict__ ko,
                                                  unsigned short* __restrict__ vo) {
    __shared__ unsigned short As[2 * 128 * 32];       // [khalf][row][32]
    __shared__ unsigned short Bs[3 * 2 * 64 * 32];    // [mat][khalf][row][32]
    const int head = blockIdx.x;
    const int m0 = blockIdx.y << 7;
    const int tid = threadIdx.x;
    const int wave = tid >> 6, lane = tid & 63;
    const int lm = lane & 15, kq = lane >> 4;

#pragma unroll
    for (int j = 0; j < 4; ++j) {
        int khalf = j >> 1;
        int rem = (j & 1) * 256 + tid;           // 0..511
        int row = rem >> 2, koff = (rem & 3) * 8;
        gl_lds16(h + (size_t)(m0 + row) * DD + head * 64 + khalf * 32 + koff,
                 &As[(j * 256 + tid) * 8]);
    }
    const unsigned short* Wq_h = Wqb + head * 4096;
    const unsigned short* Wk_h = Wkb + head * 4096;
    const unsigned short* Wv_h = Wvb + head * 4096;
#pragma unroll
    for (int j = 0; j < 6; ++j) {
        const unsigned short* src = (j < 2) ? Wq_h : ((j < 4) ? Wk_h : Wv_h);
        int cm = (j & 1) * 256 + tid;            // 0..511 within mat
        int khalf = cm >> 8;
        int rem2 = cm & 255;
        int row = rem2 >> 2, koff = (rem2 & 3) * 8;
        gl_lds16(src + row * 64 + khalf * 32 + koff, &Bs[(j * 256 + tid) * 8]);
    }
    __syncthreads();

    f4_t acc[2][12];
#pragma unroll
    for (int i = 0; i < 2; ++i)
#pragma unroll
        for (int j = 0; j < 12; ++j) acc[i][j] = (f4_t){0.f, 0.f, 0.f, 0.f};

#pragma unroll
    for (int kh = 0; kh < 2; ++kh) {
        bf8_t af[2], bfr[12];
#pragma unroll
        for (int mt = 0; mt < 2; ++mt)
            af[mt] = *(const bf8_t*)&As[kh * 4096 + (wave * 32 + mt * 16 + lm) * 32 + kq * 8];
#pragma unroll
        for (int nt = 0; nt < 12; ++nt)
            bfr[nt] = *(const bf8_t*)&Bs[(nt >> 2) * 4096 + kh * 2048 +
                                         ((nt & 3) * 16 + lm) * 32 + kq * 8];
#pragma unroll
        for (int mt = 0; mt < 2; ++mt)
#pragma unroll
            for (int nt = 0; nt < 12; ++nt)
                acc[mt][nt] = __builtin_amdgcn_mfma_f32_16x16x32_bf16(af[mt], bfr[nt],
                                                                      acc[mt][nt], 0, 0, 0);
    }

    const int rbase = m0 + wave * 32 + kq * 4;
#pragma unroll
    for (int mt = 0; mt < 2; ++mt) {
#pragma unroll
        for (int nt = 0; nt < 12; ++nt) {
            const int col = nt * 16 + lm;
            const int e = col & 63;
            const float* bsrc = (nt < 4) ? bq : ((nt < 8) ? bk : bv);
            unsigned short* dst = (nt < 4) ? qo : ((nt < 8) ? ko : vo);
            const float bval = bsrc[head * 64 + e];
#pragma unroll
            for (int r = 0; r < 4; ++r) {
                const int row = rbase + mt * 16 + r;
                if (row < NTOK)
                    dst[(size_t)row * DD + head * 64 + e] = f2bf(acc[mt][nt][r] + bval);
            }
        }
    }
}

// =====================================================================
// pos-embed add (+cls for s==0)
// =====================================================================
__global__ __launch_bounds__(256) void k_posadd(float* __restrict__ x,
                                                const float* __restrict__ cls) {
    const int total = BB * SS * DD;
    const float LN1E4 = 9.210340371976184f;
    for (int idx = blockIdx.x * 256 + threadIdx.x; idx < total; idx += gridDim.x * 256) {
        int d = idx % DD;
        int s = (idx / DD) % SS;
        float ang = (float)s * __expf(-LN1E4 * (float)(2 * (d >> 1)) / 768.f);
        float pv = (d & 1) ? __cosf(ang) : __sinf(ang);
        if (s == 0) x[idx] = cls[d] + pv;
        else        x[idx] += pv;
    }
}

// =====================================================================
// LayerNorm: wave per row (4 rows/block), lane holds 12 elems, bf16 out
// =====================================================================
__global__ __launch_bounds__(256) void k_ln2(const float* __restrict__ x,
                                             const float* __restrict__ g,
                                             const float* __restrict__ bp,
                                             unsigned short* __restrict__ out) {
    const int row = blockIdx.x * 4 + (threadIdx.x >> 6);
    const int lane = threadIdx.x & 63;
    if (row >= NTOK) return;
    const float* xr = x + (size_t)row * DD + lane * 12;
    float4 a = ((const float4*)xr)[0];
    float4 b = ((const float4*)xr)[1];
    float4 c = ((const float4*)xr)[2];
    float s = a.x + a.y + a.z + a.w + b.x + b.y + b.z + b.w + c.x + c.y + c.z + c.w;
#pragma unroll
    for (int o = 32; o; o >>= 1) s += __shfl_xor(s, o);
    const float mean = s * (1.f / DD);
    float vr = 0.f, e0;
    e0 = a.x - mean; vr += e0 * e0; e0 = a.y - mean; vr += e0 * e0;
    e0 = a.z - mean; vr += e0 * e0; e0 = a.w - mean; vr += e0 * e0;
    e0 = b.x - mean; vr += e0 * e0; e0 = b.y - mean; vr += e0 * e0;
    e0 = b.z - mean; vr += e0 * e0; e0 = b.w - mean; vr += e0 * e0;
    e0 = c.x - mean; vr += e0 * e0; e0 = c.y - mean; vr += e0 * e0;
    e0 = c.z - mean; vr += e0 * e0; e0 = c.w - mean; vr += e0 * e0;
#pragma unroll
    for (int o = 32; o; o >>= 1) vr += __shfl_xor(vr, o);
    const float rstd = rsqrtf(vr * (1.f / DD) + LNEPS);

    const float4* g4 = (const float4*)(g + lane * 12);
    const float4* b4p = (const float4*)(bp + lane * 12);
    unsigned short* op = out + (size_t)row * DD + lane * 12;
    float4 gv, bv;
    ushort4 r;
    gv = g4[0]; bv = b4p[0];
    r.x = f2bf((a.x - mean) * rstd * gv.x + bv.x);
    r.y = f2bf((a.y - mean) * rstd * gv.y + bv.y);
    r.z = f2bf((a.z - mean) * rstd * gv.z + bv.z);
    r.w = f2bf((a.w - mean) * rstd * gv.w + bv.w);
    ((ushort4*)op)[0] = r;
    gv = g4[1]; bv = b4p[1];
    r.x = f2bf((b.x - mean) * rstd * gv.x + bv.x);
    r.y = f2bf((b.y - mean) * rstd * gv.y + bv.y);
    r.z = f2bf((b.z - mean) * rstd * gv.z + bv.z);
    r.w = f2bf((b.w - mean) * rstd * gv.w + bv.w);
    ((ushort4*)op)[1] = r;
    gv = g4[2]; bv = b4p[2];
    r.x = f2bf((c.x - mean) * rstd * gv.x + bv.x);
    r.y = f2bf((c.y - mean) * rstd * gv.y + bv.y);
    r.z = f2bf((c.z - mean) * rstd * gv.z + bv.z);
    r.w = f2bf((c.w - mean) * rstd * gv.w + bv.w);
    ((ushort4*)op)[2] = r;
}

// =====================================================================
// attention v3 (MFMA): block = (64-query tile, head, b), 256 thr = 4 waves.
// =====================================================================
__global__ __launch_bounds__(256) void k_attn3(const unsigned short* __restrict__ qg,
                                               const unsigned short* __restrict__ kg,
                                               const unsigned short* __restrict__ vg,
                                               float* __restrict__ x) {
    const int qt = blockIdx.x, head = blockIdx.y, b = blockIdx.z;
    const int tid = threadIdx.x, wv = tid >> 6, lane = tid & 63;
    const int lm = lane & 15, kq = lane >> 4;

    __shared__ __align__(16) unsigned short lds[29696];   // 59392 B
    unsigned short* Kl = lds;            // [kh][224][32] = 14336 sh
    unsigned short* Pl = lds;            // [4][16][232]  = 14848 sh (aliases K)
    unsigned short* Vt = lds + 14848;    // [64][232]     = 14848 sh

    const size_t tokbase = (size_t)b * SS;
    const unsigned short* kb = kg + tokbase * DD + head * 64;
    const unsigned short* vb = vg + tokbase * DD + head * 64;
    const unsigned short* qb = qg + tokbase * DD + head * 64;

    // ---- stage K: [kh][t(224)][32], 1792 x 16B chunks via global_load_lds ----
#pragma unroll
    for (int it = 0; it < 7; ++it) {
        int c = it * 256 + tid;
        int kh = c / 896, rem = c - kh * 896;
        int t = rem >> 2, cc = rem & 3;
        gl_lds16(kb + (size_t)t * DD + kh * 32 + cc * 8, (char*)lds + c * 16);
    }
    // ---- stage V transposed: Vt[e][t], t padded 224 (197.. zeroed) ----
#pragma unroll
    for (int it = 0; it < 7; ++it) {
        int idx = it * 256 + tid;
        int t = idx >> 3, eg = idx & 7;
        if (t < SS) {
            u16x8 v8 = *(const u16x8*)(vb + (size_t)t * DD + eg * 8);
#pragma unroll
            for (int j = 0; j < 8; ++j) Vt[(eg * 8 + j) * 232 + t] = v8[j];
        } else {
#pragma unroll
            for (int j = 0; j < 8; ++j) Vt[(eg * 8 + j) * 232 + t] = 0;
        }
    }

    // ---- Q fragments (B-operand) straight from global ----
    const int qrow = qt * 64 + wv * 16 + lm;
    bf8_t qf0 = *(const bf8_t*)(qb + (size_t)qrow * DD + kq * 8);
    bf8_t qf1 = *(const bf8_t*)(qb + (size_t)qrow * DD + 32 + kq * 8);

    __syncthreads();

    // ---- S^T: D[t-tile][q16] ; 13 t-tiles x 2 kh ----
    f4_t sacc[13];
#pragma unroll
    for (int tt = 0; tt < 13; ++tt) sacc[tt] = (f4_t){0.f, 0.f, 0.f, 0.f};
#pragma unroll
    for (int tt = 0; tt < 13; ++tt) {
        bf8_t a0 = *(const bf8_t*)&Kl[(tt * 16 + lm) * 32 + kq * 8];
        bf8_t a1 = *(const bf8_t*)&Kl[7168 + (tt * 16 + lm) * 32 + kq * 8];
        sacc[tt] = __builtin_amdgcn_mfma_f32_16x16x32_bf16(a0, qf0, sacc[tt], 0, 0, 0);
        sacc[tt] = __builtin_amdgcn_mfma_f32_16x16x32_bf16(a1, qf1, sacc[tt], 0, 0, 0);
    }

    // ---- softmax over t for q = lm ----
    float mx = -1e30f;
#pragma unroll
    for (int tt = 0; tt < 13; ++tt)
#pragma unroll
        for (int r = 0; r < 4; ++r) {
            float s = sacc[tt][r] * 0.125f;
            if (tt == 12 && (kq * 4 + r) >= 5) s = -1e30f;   // t >= 197
            sacc[tt][r] = s;
            mx = fmaxf(mx, s);
        }
    mx = fmaxf(mx, __shfl_xor(mx, 16));
    mx = fmaxf(mx, __shfl_xor(mx, 32));
    float sum = 0.f;
#pragma unroll
    for (int tt = 0; tt < 13; ++tt)
#pragma unroll
        for (int r = 0; r < 4; ++r) {
            float p = __expf(sacc[tt][r] - mx);
            sacc[tt][r] = p;
            sum += p;
        }
    sum += __shfl_xor(sum, 16);
    sum += __shfl_xor(sum, 32);
    const float inv = 1.f / sum;

    __syncthreads();   // all waves done reading K -> safe to overwrite with P

    // ---- write P (A-layout rows [q][t], per-wave region) ----
    unsigned short* Pw = Pl + wv * 3712;
#pragma unroll
    for (int tt = 0; tt < 13; ++tt)
#pragma unroll
        for (int r = 0; r < 4; ++r)
            Pw[lm * 232 + tt * 16 + kq * 4 + r] = f2bf(sacc[tt][r]);
    *(short4*)&Pw[lm * 232 + 208 + kq * 4] = make_short4(0, 0, 0, 0);

    // ---- PV: O[q][e] ; 7 k-chunks x 4 e-tiles ----
    f4_t oacc[4];
#pragma unroll
    for (int et = 0; et < 4; ++et) oacc[et] = (f4_t){0.f, 0.f, 0.f, 0.f};
#pragma unroll
    for (int kc = 0; kc < 7; ++kc) {
        bf8_t pa = *(const bf8_t*)&Pw[lm * 232 + kc * 32 + kq * 8];
#pragma unroll
        for (int et = 0; et < 4; ++et) {
            bf8_t vv = *(const bf8_t*)&Vt[(et * 16 + lm) * 232 + kc * 32 + kq * 8];
            oacc[et] = __builtin_amdgcn_mfma_f32_16x16x32_bf16(pa, vv, oacc[et], 0, 0, 0);
        }
    }

    // ---- 1/sum redistribution (softmax layout q=lm -> C layout q=kq*4+r) ----
    float invq[4];
#pragma unroll
    for (int r = 0; r < 4; ++r) invq[r] = __shfl(inv, kq * 4 + r);

    // ---- residual add into x ----
    float* xp = x + tokbase * DD + head * 64;
#pragma unroll
    for (int r = 0; r < 4; ++r) {
        const int qgr = qt * 64 + wv * 16 + kq * 4 + r;
        if (qgr < SS) {
#pragma unroll
            for (int et = 0; et < 4; ++et)
                xp[(size_t)qgr * DD + et * 16 + lm] += oacc[et][r] * invq[r];
        }
    }
}

// =====================================================================
// classifier head (fp32)
// =====================================================================
__global__ __launch_bounds__(256) void k_head(const float* __restrict__ x,
                                              const float* __restrict__ Wh,
                                              const float* __restrict__ bh,
                                              float* __restrict__ out) {
    const int b = blockIdx.y;
    const int c = blockIdx.x * 256 + threadIdx.x;
    __shared__ __align__(16) float xs[DD];
    const float* xr = x + (size_t)b * SS * DD;
    for (int d = threadIdx.x; d < DD; d += 256) xs[d] = xr[d];
    __syncthreads();
    if (c < 1000) {
        const float4* w4 = (const float4*)(Wh + (size_t)c * DD);
        float acc = 0.f;
#pragma unroll 4
        for (int d4 = 0; d4 < DD / 4; ++d4) {
            float4 w = w4[d4];
            const float4 xv = *(const float4*)&xs[d4 << 2];
            acc += xv.x * w.x + xv.y * w.y + xv.z * w.z + xv.w * w.w;
        }
        out[(size_t)b * 1000 + c] = acc + bh[c];
    }
}

// =====================================================================
extern "C" void kernel_launch(void* const* d_in, const int* in_sizes, int n_in,
                              void* d_out, int out_size, void* d_ws, size_t ws_size,
                              hipStream_t stream) {
    const float* image   = (const float*)d_in[0];
    const float* W_embed = (const float*)d_in[1];
    const float* b_embed = (const float*)d_in[2];
    const float* cls     = (const float*)d_in[3];
    const float* Wq      = (const float*)d_in[4];
    const float* bq      = (const float*)d_in[5];
    const float* Wk      = (const float*)d_in[6];
    const float* bk      = (const float*)d_in[7];
    const float* Wv      = (const float*)d_in[8];
    const float* bv      = (const float*)d_in[9];
    const float* ln1g    = (const float*)d_in[10];
    const float* ln1b    = (const float*)d_in[11];
    const float* ln2g    = (const float*)d_in[12];
    const float* ln2b    = (const float*)d_in[13];
    const float* W1      = (const float*)d_in[14];
    const float* b1      = (const float*)d_in[15];
    const float* W2      = (const float*)d_in[16];
    const float* b2      = (const float*)d_in[17];
    const float* Wh      = (const float*)d_in[18];
    const float* bh      = (const float*)d_in[19];
    float* out = (float*)d_out;

    float* x = (float*)d_ws;
    unsigned short* h_bf   = (unsigned short*)(x + (size_t)NTOK * DD);
    unsigned short* q_bf   = h_bf + (size_t)MPAD * DD;
    unsigned short* k_bf   = q_bf + (size_t)MPAD * DD;
    unsigned short* v_bf   = k_bf + (size_t)MPAD * DD;
    unsigned short* mlp_bf = v_bf + (size_t)MPAD * DD;            // MPAD*FF
    unsigned short* W1_bf  = mlp_bf + (size_t)MPAD * FF;
    unsigned short* W2_bf  = W1_bf + (size_t)FF * DD;
    unsigned short* We_bf  = W2_bf + (size_t)FF * DD;
    unsigned short* Wq_bf  = We_bf + (size_t)DD * DD;             // L*H*64*64
    unsigned short* Wk_bf  = Wq_bf + (size_t)LL * HH * DHD * DHD;
    unsigned short* Wv_bf  = Wk_bf + (size_t)LL * HH * DHD * DHD;
    unsigned short* P_bf   = mlp_bf;                              // alias pre-loop

    const int QKVW = LL * HH * DHD * DHD;                         // 589824

    // one-time weight conversions
    k_conv<<<576, 256, 0, stream>>>(W_embed, We_bf, DD * DD / 4);
    k_conv<<<576, 256, 0, stream>>>(Wq, Wq_bf, QKVW / 4);
    k_conv<<<576, 256, 0, stream>>>(Wk, Wk_bf, QKVW / 4);
    k_conv<<<576, 256, 0, stream>>>(Wv, Wv_bf, QKVW / 4);

    // embed
    k_patchify<<<1024, 256, 0, stream>>>(image, P_bf);
    k_gemm_bf<0><<<dim3(6, 49), 256, 0, stream>>>(P_bf, We_bf, b_embed, x,
                                                  BB * NPATCH, DD, DD);
    k_posadd<<<1024, 256, 0, stream>>>(x, cls);

    for (int l = 0; l < LL; ++l) {
        k_ln2<<<(NTOK + 3) / 4, 256, 0, stream>>>(x, ln1g + l * DD, ln1b + l * DD, h_bf);
        k_qkv_mfma<<<dim3(HH, MPAD / 128), 256, 0, stream>>>(
            h_bf, Wq_bf + (size_t)l * HH * 4096, Wk_bf + (size_t)l * HH * 4096,
            Wv_bf + (size_t)l * HH * 4096, bq + l * DD, bk + l * DD, bv + l * DD,
            q_bf, k_bf, v_bf);
        k_attn3<<<dim3(4, HH, BB), 256, 0, stream>>>(q_bf, k_bf, v_bf, x);
        k_ln2<<<(NTOK + 3) / 4, 256, 0, stream>>>(x, ln2g + l * DD, ln2b + l * DD, h_bf);
        k_conv2<<<2048, 256, 0, stream>>>(W1 + (size_t)l * FF * DD, W1_bf, FF * DD / 4,
                                          W2 + (size_t)l * DD * FF, W2_bf, FF * DD / 4);
        k_gemm_bf<1><<<dim3(FF / 128, MPAD / 128), 256, 0, stream>>>(
            h_bf, W1_bf, b1 + (size_t)l * FF, mlp_bf, NTOK, FF, DD);
        k_gemm_w2<<<dim3(DD / 64, MPAD / 128), 256, 0, stream>>>(
            mlp_bf, W2_bf, b2 + (size_t)l * DD, x, NTOK, FF);
    }

    k_head<<<dim3(4, BB), 256, 0, stream>>>(x, Wh, bh, out);
}